// Round 6
// baseline (227.204 us; speedup 1.0000x reference)
//
#include <hip/hip_runtime.h>
#include <hip/hip_bf16.h>

#define B_ 8
#define S_ 1024
#define U_ 1024
#define H_ 16
#define DK_ 64

typedef __attribute__((ext_vector_type(8))) short short8;
typedef __attribute__((ext_vector_type(4))) float f32x4;
typedef __attribute__((ext_vector_type(16))) float f32x16;

__device__ inline ushort f2b(float x) {
  union { float f; unsigned u; } v; v.f = x;
  unsigned r = (v.u + 0x7FFFu + ((v.u >> 16) & 1u)) >> 16;
  return (ushort)r;
}
__device__ inline unsigned pk2(float lo, float hi) {
  return (unsigned)f2b(lo) | ((unsigned)f2b(hi) << 16);
}

__device__ inline void gld16(const ushort* g, ushort* l) {
  __builtin_amdgcn_global_load_lds((__attribute__((address_space(1))) void*)(g),
                                   (__attribute__((address_space(3))) void*)(l),
                                   16, 0, 0);
}

// ---------------- pack query fp32 -> bf16 ----------------
__global__ __launch_bounds__(256) void pack_x_kern(const float* __restrict__ X,
                                                   ushort* __restrict__ Xb) {
  int idx = blockIdx.x * 256 + threadIdx.x;
  const float4* src = (const float4*)X + (size_t)idx * 2;
  float4 a = src[0], b = src[1];
  ushort r[8];
  r[0]=f2b(a.x); r[1]=f2b(a.y); r[2]=f2b(a.z); r[3]=f2b(a.w);
  r[4]=f2b(b.x); r[5]=f2b(b.y); r[6]=f2b(b.z); r[7]=f2b(b.w);
  *(uint4*)(Xb + (size_t)idx*8) = *(uint4*)r;
}

// ---------------- pack weights (transpose to [n][k], bf16) ----------------
__global__ __launch_bounds__(256) void pack_w_kern(
    const float* __restrict__ Wq, const float* __restrict__ Wk, const float* __restrict__ Wv,
    const float* __restrict__ bq, const float* __restrict__ bk, const float* __restrict__ bv,
    const float* __restrict__ Wo,
    ushort* __restrict__ Wqkv, float* __restrict__ Bqkv, ushort* __restrict__ Wob)
{
  __shared__ ushort tile[64*65];
  const int t = threadIdx.x;
  const int bid = blockIdx.x;
  if (bid < 768) {
    int p = bid >> 8, rem = bid & 255;
    int h = rem >> 4, kc = rem & 15, k0 = kc*64;
    const float* Wsrc = (p==0) ? Wq : ((p==1) ? Wk : Wv);
    #pragma unroll
    for (int i = 0; i < 16; ++i) {
      int e = t + i*256;
      int r = e >> 6, d = e & 63;
      tile[d*65 + r] = f2b(Wsrc[h*65536 + (k0+r)*64 + d]);
    }
    __syncthreads();
    #pragma unroll
    for (int i = 0; i < 16; ++i) {
      int e = t + i*256;
      int d = e >> 6, r = e & 63;
      Wqkv[(size_t)(p*1024 + h*64 + d)*1024 + k0 + r] = tile[d*65 + r];
    }
    if (kc == 0 && t < 64) {
      const float* bsrc = (p==0) ? bq : ((p==1) ? bk : bv);
      Bqkv[p*1024 + h*64 + t] = bsrc[h*64 + t];
    }
  } else {
    int b2 = bid - 768;
    int nc = b2 >> 4, kc = b2 & 15;
    int n0 = nc*64, k0 = kc*64;
    #pragma unroll
    for (int i = 0; i < 16; ++i) {
      int e = t + i*256;
      int r = e >> 6, d = e & 63;
      tile[d*65 + r] = f2b(Wo[(size_t)(k0+r)*1024 + n0 + d]);
    }
    __syncthreads();
    #pragma unroll
    for (int i = 0; i < 16; ++i) {
      int e = t + i*256;
      int d = e >> 6, r = e & 63;
      Wob[(size_t)(n0+d)*1024 + k0 + r] = tile[d*65 + r];
    }
  }
}

// ------------- GEMM: 256-row tile, counted-vmcnt deep pipeline (T3+T4+T5) ----
// 512 thr = 8 waves (2M x 4N). BK=32, double-buffered, 2-tile-deep prefetch:
// per iter: vmcnt(LOADS) [counted, NEVER 0] -> raw s_barrier -> 4 quadrant
// phases {ds_read frags, setprio(1), MFMA, setprio(0)} -> raw s_barrier ->
// stage tile t+2. LDS tiles in FRAGMENT ORDER (pre-permuted global source) so
// every fragment read is base+lane*16 => conflict-free.
// MODE 0: BN=256, QKV proj -> Q (scaled 0.125*log2e) [bh][s][d], K [bh][s][d],
//         V transposed [bh][d][s].  MODE 1: BN=128, out proj -> fp32.
template<int MODE>
__global__ __launch_bounds__(512, 2) void gemm256_kern(
    const ushort* __restrict__ A,
    const ushort* __restrict__ Bw,
    const float* __restrict__ bias,
    ushort* __restrict__ Qb, ushort* __restrict__ Kb, ushort* __restrict__ Vtb,
    float* __restrict__ outF)
{
  constexpr int BN  = (MODE==0) ? 256 : 128;
  constexpr int NJ  = BN/64;            // n-frags per wave (4 or 2)
  constexpr int NPB = BN*4/512;         // B staging parts (2 or 1)
  constexpr int PX  = (MODE==0) ? 48 : 32;  // blocks per XCD

  __shared__ __align__(16) ushort As[2][8192];
  __shared__ __align__(16) ushort Bs[2][BN*32];

  const int t = threadIdx.x;
  const int l = t & 63, w = t >> 6;
  const int wr = w >> 2, wc = w & 3;
  const int li = l & 15, c4 = l >> 4;

  const int gid = (blockIdx.x & 7) * PX + (blockIdx.x >> 3);
  const int m0 = (gid & 31) * 256;
  const int n0 = (gid >> 5) * BN;

  f32x4 acc[8][NJ];
  #pragma unroll
  for (int i=0;i<8;i++)
    #pragma unroll
    for (int j=0;j<NJ;j++) acc[i][j] = (f32x4)0.0f;

  auto STAGE = [&](int buf, int kk) {
    #pragma unroll
    for (int p = 0; p < 2; ++p) {
      int n = p*512 + t;
      gld16(&A[(size_t)(m0 + ((n>>6)<<4) + (n&15))*1024 + kk + ((n>>4)&3)*8],
            &As[buf][n*8]);
    }
    #pragma unroll
    for (int p = 0; p < NPB; ++p) {
      int n = p*512 + t;
      gld16(&Bw[(size_t)(n0 + ((n>>6)<<4) + (n&15))*1024 + kk + ((n>>4)&3)*8],
            &Bs[buf][n*8]);
    }
  };

  STAGE(0, 0);
  STAGE(1, 32);

  #pragma unroll 2
  for (int kt = 0; kt < 32; ++kt) {
    const int cur = kt & 1;
    if constexpr (MODE==0) asm volatile("s_waitcnt vmcnt(4)" ::: "memory");
    else                   asm volatile("s_waitcnt vmcnt(3)" ::: "memory");
    __builtin_amdgcn_s_barrier();
    __builtin_amdgcn_sched_barrier(0);

    #pragma unroll
    for (int qm = 0; qm < 2; ++qm) {
      short8 af[4];
      #pragma unroll
      for (int i=0;i<4;i++) {
        int i2 = wr*8 + qm*4 + i;
        af[i] = *(const short8*)&As[cur][i2*512 + l*8];
      }
      #pragma unroll
      for (int qn = 0; qn < 2; ++qn) {
        short8 bf[NJ/2];
        #pragma unroll
        for (int jj=0;jj<NJ/2;jj++) {
          int j2 = wc*NJ + qn*(NJ/2) + jj;
          bf[jj] = *(const short8*)&Bs[cur][j2*512 + l*8];
        }
        __builtin_amdgcn_s_setprio(1);
        #pragma unroll
        for (int i=0;i<4;i++)
          #pragma unroll
          for (int jj=0;jj<NJ/2;jj++)
            acc[qm*4+i][qn*(NJ/2)+jj] =
              __builtin_amdgcn_mfma_f32_16x16x32_bf16(af[i], bf[jj],
                                                      acc[qm*4+i][qn*(NJ/2)+jj], 0, 0, 0);
        __builtin_amdgcn_s_setprio(0);
      }
    }

    __builtin_amdgcn_sched_barrier(0);
    __builtin_amdgcn_s_barrier();
    __builtin_amdgcn_sched_barrier(0);
    const int kk2 = (kt + 2 < 32) ? (kt + 2) * 32 : 0;   // dummy on tail
    STAGE(cur, kk2);
  }

  #pragma unroll
  for (int i=0;i<8;i++) {
    int rbase = m0 + wr*128 + i*16 + c4*4;
    #pragma unroll
    for (int j=0;j<NJ;j++) {
      int col = n0 + wc*(BN/4) + j*16 + li;
      float bv = bias[col];
      if (MODE == 0) {
        int p = col >> 10, h = (col >> 6) & 15, d = col & 63;
        int b = rbase >> 10, s = rbase & 1023;
        if (p == 2) {          // V -> transposed [bh][d][s], 8B packed store
          ushort pk4[4];
          #pragma unroll
          for (int r=0;r<4;r++) pk4[r] = f2b(acc[i][j][r] + bv);
          *(uint2*)&Vtb[((size_t)((b*16+h)*64 + d))*1024 + s] = *(uint2*)pk4;
        } else {
          ushort* dst = (p==0) ? Qb : Kb;
          float sc = (p==0) ? 0.18033688011112042f : 1.0f;   // 0.125*log2(e)
          #pragma unroll
          for (int r=0;r<4;r++)
            dst[(((size_t)(b*16 + h))*1024 + s + r)*64 + d] = f2b((acc[i][j][r] + bv) * sc);
        }
      } else {
        #pragma unroll
        for (int r=0;r<4;r++)
          outF[(size_t)(rbase+r)*1024 + col] = acc[i][j][r] + bv;
      }
    }
  }
}

// ---------------- causal flash attention, wave-independent ----------------
// 1024 blocks x 256 thr; wave w handles q-tile {j,15-j,16+j,31-j}[w] of head bh.
// No __syncthreads. 32x32x16 MFMAs; swapped QK^T (S[kv][q]) and swapped PV
// (O[d][q]) so softmax state is per-lane scalar + one shfl_xor(32).
// Scores in log2 domain (scale folded into Q).
__global__ __launch_bounds__(256, 3) void attn_kern(
    const ushort* __restrict__ Qb, const ushort* __restrict__ Kb,
    const ushort* __restrict__ Vt, ushort* __restrict__ Ob)
{
  __shared__ __align__(16) ushort Pb[4][32*40];   // per-wave P [q][kv], stride 40
  __shared__ __align__(16) ushort OT[4][32*72];   // per-wave epilogue transpose
  const int t = threadIdx.x, l = t & 63, w = t >> 6;
  const int bid = blockIdx.x;
  const int x = bid & 7, i0 = bid >> 3;
  const int bh = x*16 + (i0 >> 3), j = i0 & 7;     // bh clustered per XCD
  int qt;
  if      (w == 0) qt = j;
  else if (w == 1) qt = 15 - j;
  else if (w == 2) qt = 16 + j;
  else             qt = 31 - j;

  const int col = l & 31, hi = l >> 5;
  const ushort* Qp = Qb + (size_t)bh*65536;
  const ushort* Kp = Kb + (size_t)bh*65536;
  const ushort* Vp = Vt + (size_t)bh*65536;

  short8 qf[4];
  #pragma unroll
  for (int m=0;m<4;m++)
    qf[m] = *(const short8*)&Qp[(size_t)(qt*32+col)*64 + m*16 + hi*8];

  f32x16 accO0 = (f32x16)0.0f, accO1 = (f32x16)0.0f;
  float mR = -1e30f, lS = 0.0f;

  ushort* Pw = &Pb[w][0];
  const int nt = qt + 1;
  for (int kt = 0; kt < nt; ++kt) {
    short8 kf[4], vf0[2], vf1[2];
    #pragma unroll
    for (int m=0;m<4;m++)
      kf[m] = *(const short8*)&Kp[(size_t)(kt*32+col)*64 + m*16 + hi*8];
    #pragma unroll
    for (int m=0;m<2;m++) {
      vf0[m] = *(const short8*)&Vp[(size_t)col*1024      + kt*32 + m*16 + hi*8];
      vf1[m] = *(const short8*)&Vp[(size_t)(32+col)*1024 + kt*32 + m*16 + hi*8];
    }

    f32x16 s = (f32x16)0.0f;
    #pragma unroll
    for (int m=0;m<4;m++)
      s = __builtin_amdgcn_mfma_f32_32x32x16_bf16(kf[m], qf[m], s, 0, 0, 0);

    if (kt == qt) {                       // diagonal tile: causal mask
      #pragma unroll
      for (int r=0;r<16;r++) {
        int kvl = (r&3) + ((r>>2)<<3) + 4*hi;
        s[r] = (kvl > col) ? -1e9f : s[r];
      }
    }

    float mx = s[0];
    #pragma unroll
    for (int r=1;r<16;r++) mx = fmaxf(mx, s[r]);
    mx = fmaxf(mx, __shfl_xor(mx, 32));   // combine kv-halves (lane i <-> i+32)

    if (__any(mx - mR > 8.0f)) {          // T13 defer-max (log2 units)
      float mN = fmaxf(mR, mx);
      float corr = __builtin_amdgcn_exp2f(mR - mN);
      mR = mN; lS *= corr;
      #pragma unroll
      for (int r=0;r<16;r++) { accO0[r] *= corr; accO1[r] *= corr; }
    }

    float p[16], rs = 0.0f;
    #pragma unroll
    for (int r=0;r<16;r++) { p[r] = __builtin_amdgcn_exp2f(s[r] - mR); rs += p[r]; }
    rs += __shfl_xor(rs, 32);
    lS += rs;

    // P -> per-wave LDS [q][kv] (packed pair writes), then B-fragment reads
    #pragma unroll
    for (int r2=0;r2<8;r2++) {
      int r = 2*r2;
      int kv = (r&3) + ((r>>2)<<3) + 4*hi;          // even; pair (kv, kv+1)
      *(unsigned*)&Pw[col*40 + kv] = pk2(p[r], p[r+1]);
    }
    short8 pb0 = *(const short8*)&Pw[col*40 + hi*8];        // kv 0..15 slice
    short8 pb1 = *(const short8*)&Pw[col*40 + 16 + hi*8];   // kv 16..31 slice

    accO0 = __builtin_amdgcn_mfma_f32_32x32x16_bf16(vf0[0], pb0, accO0, 0,0,0);
    accO0 = __builtin_amdgcn_mfma_f32_32x32x16_bf16(vf0[1], pb1, accO0, 0,0,0);
    accO1 = __builtin_amdgcn_mfma_f32_32x32x16_bf16(vf1[0], pb0, accO1, 0,0,0);
    accO1 = __builtin_amdgcn_mfma_f32_32x32x16_bf16(vf1[1], pb1, accO1, 0,0,0);
  }

  // epilogue: O[dv][q] regs -> LDS transpose -> coalesced global store
  float inv = 1.0f / lS;
  ushort* o = &OT[w][0];
  #pragma unroll
  for (int r2=0;r2<8;r2++) {
    int r = 2*r2;
    int dv = (r&3) + ((r>>2)<<3) + 4*hi;
    *(unsigned*)&o[col*72 + dv]      = pk2(accO0[r]*inv, accO0[r+1]*inv);
    *(unsigned*)&o[col*72 + 32 + dv] = pk2(accO1[r]*inv, accO1[r+1]*inv);
  }
  const int b = bh >> 4, h = bh & 15;
  #pragma unroll
  for (int it=0; it<4; ++it) {
    int q = it*8 + (l>>3), c8 = (l&7)*8;
    uint4 v = *(const uint4*)&o[q*72 + c8];
    int qg = qt*32 + q;
    *(uint4*)&Ob[(size_t)(b*1024+qg)*1024 + h*64 + c8] = v;
  }
}

extern "C" void kernel_launch(void* const* d_in, const int* in_sizes, int n_in,
                              void* d_out, int out_size, void* d_ws, size_t ws_size,
                              hipStream_t stream) {
  const float* query = (const float*)d_in[0];
  const float* Wq = (const float*)d_in[4];
  const float* bq = (const float*)d_in[5];
  const float* Wk = (const float*)d_in[6];
  const float* bk = (const float*)d_in[7];
  const float* Wv = (const float*)d_in[8];
  const float* bv = (const float*)d_in[9];
  const float* Wo = (const float*)d_in[10];
  const float* bo = (const float*)d_in[11];

  char* wsb = (char*)d_ws;
  ushort* Xb   = (ushort*)(wsb);                  // 16 MB
  ushort* Wqkv = (ushort*)(wsb + 16777216);       // 6 MB
  float*  Bqkv = (float*) (wsb + 23068672);       // 12 KB
  ushort* Wob  = (ushort*)(wsb + 23080960);       // 2 MB
  ushort* Qb   = (ushort*)(wsb + 25178112);       // 16 MB
  ushort* Kb   = (ushort*)(wsb + 41955328);       // 16 MB
  ushort* Vtb  = (ushort*)(wsb + 58732544);       // 16 MB  [bh][d][s]
  ushort* Ob   = (ushort*)(wsb + 75509760);       // 16 MB

  hipLaunchKernelGGL(pack_x_kern, dim3(4096), dim3(256), 0, stream, query, Xb);
  hipLaunchKernelGGL(pack_w_kern, dim3(1024), dim3(256), 0, stream,
                     Wq, Wk, Wv, bq, bk, bv, Wo, Wqkv, Bqkv, Wob);
  hipLaunchKernelGGL(gemm256_kern<0>, dim3(384), dim3(512), 0, stream,
                     Xb, Wqkv, Bqkv, Qb, Kb, Vtb, (float*)nullptr);
  hipLaunchKernelGGL(attn_kern, dim3(1024), dim3(256), 0, stream, Qb, Kb, Vtb, Ob);
  hipLaunchKernelGGL(gemm256_kern<1>, dim3(256), dim3(512), 0, stream,
                     Ob, Wob, bo, (ushort*)nullptr, (ushort*)nullptr, (ushort*)nullptr,
                     (float*)d_out);
}

// Round 7
// 182.788 us; speedup vs baseline: 1.2430x; 1.2430x over previous
//
#include <hip/hip_runtime.h>
#include <hip/hip_bf16.h>

#define B_ 8
#define S_ 1024
#define U_ 1024
#define H_ 16
#define DK_ 64

typedef __attribute__((ext_vector_type(8))) short short8;
typedef __attribute__((ext_vector_type(4))) float f32x4;
typedef __attribute__((ext_vector_type(16))) float f32x16;

__device__ inline ushort f2b(float x) {
  union { float f; unsigned u; } v; v.f = x;
  unsigned r = (v.u + 0x7FFFu + ((v.u >> 16) & 1u)) >> 16;
  return (ushort)r;
}
__device__ inline unsigned pk2(float lo, float hi) {
  return (unsigned)f2b(lo) | ((unsigned)f2b(hi) << 16);
}

__device__ inline void gld16(const ushort* g, ushort* l) {
  __builtin_amdgcn_global_load_lds((__attribute__((address_space(1))) void*)(g),
                                   (__attribute__((address_space(3))) void*)(l),
                                   16, 0, 0);
}

// ---------------- pack query fp32 -> bf16 ----------------
__global__ __launch_bounds__(256) void pack_x_kern(const float* __restrict__ X,
                                                   ushort* __restrict__ Xb) {
  int idx = blockIdx.x * 256 + threadIdx.x;
  const float4* src = (const float4*)X + (size_t)idx * 2;
  float4 a = src[0], b = src[1];
  ushort r[8];
  r[0]=f2b(a.x); r[1]=f2b(a.y); r[2]=f2b(a.z); r[3]=f2b(a.w);
  r[4]=f2b(b.x); r[5]=f2b(b.y); r[6]=f2b(b.z); r[7]=f2b(b.w);
  *(uint4*)(Xb + (size_t)idx*8) = *(uint4*)r;
}

// ---------------- pack weights (transpose to [n][k], bf16) ----------------
__global__ __launch_bounds__(256) void pack_w_kern(
    const float* __restrict__ Wq, const float* __restrict__ Wk, const float* __restrict__ Wv,
    const float* __restrict__ bq, const float* __restrict__ bk, const float* __restrict__ bv,
    const float* __restrict__ Wo,
    ushort* __restrict__ Wqkv, float* __restrict__ Bqkv, ushort* __restrict__ Wob)
{
  __shared__ ushort tile[64*65];
  const int t = threadIdx.x;
  const int bid = blockIdx.x;
  if (bid < 768) {
    int p = bid >> 8, rem = bid & 255;
    int h = rem >> 4, kc = rem & 15, k0 = kc*64;
    const float* Wsrc = (p==0) ? Wq : ((p==1) ? Wk : Wv);
    #pragma unroll
    for (int i = 0; i < 16; ++i) {
      int e = t + i*256;
      int r = e >> 6, d = e & 63;
      tile[d*65 + r] = f2b(Wsrc[h*65536 + (k0+r)*64 + d]);
    }
    __syncthreads();
    #pragma unroll
    for (int i = 0; i < 16; ++i) {
      int e = t + i*256;
      int d = e >> 6, r = e & 63;
      Wqkv[(size_t)(p*1024 + h*64 + d)*1024 + k0 + r] = tile[d*65 + r];
    }
    if (kc == 0 && t < 64) {
      const float* bsrc = (p==0) ? bq : ((p==1) ? bk : bv);
      Bqkv[p*1024 + h*64 + t] = bsrc[h*64 + t];
    }
  } else {
    int b2 = bid - 768;
    int nc = b2 >> 4, kc = b2 & 15;
    int n0 = nc*64, k0 = kc*64;
    #pragma unroll
    for (int i = 0; i < 16; ++i) {
      int e = t + i*256;
      int r = e >> 6, d = e & 63;
      tile[d*65 + r] = f2b(Wo[(size_t)(k0+r)*1024 + n0 + d]);
    }
    __syncthreads();
    #pragma unroll
    for (int i = 0; i < 16; ++i) {
      int e = t + i*256;
      int d = e >> 6, r = e & 63;
      Wob[(size_t)(n0+d)*1024 + k0 + r] = tile[d*65 + r];
    }
  }
}

// ------- GEMM: 256-tile, BK=64, deep pipeline, counted vmcnt (T2+T3+T4+T5) ---
// 512 thr = 8 waves (2M x 4N), per-wave C = 128x64. LDS: 2 dbuf x (A,B) halves
// [128][64], linear dest for global_load_lds; XOR-slot swizzle (chunk j stored
// at slot j^(row&7)) applied on BOTH the staging source column and the ds_read
// address (rule #21) -> row staging stays coalesced, reads are <=2-way (free).
// Per K-tile iter: 4 quadrant phases {ds_read frags, setprio, 16 MFMA} (64
// MFMA total) -> s_barrier -> STAGE tile t+2 -> vmcnt(8/6) counted, NEVER 0 ->
// s_barrier. sched_barrier(0) after each s_barrier pins reads inside the safe
// window.
// MODE 0: BN=256, QKV proj -> Q (x0.125*log2e) [bh][s][d], K [bh][s][d],
//         V transposed [bh][d][s].  MODE 1: BN=128, out proj -> fp32.
template<int MODE>
__global__ __launch_bounds__(512, 2) void gemm8p_kern(
    const ushort* __restrict__ A,
    const ushort* __restrict__ Bw,
    const float* __restrict__ bias,
    ushort* __restrict__ Qb, ushort* __restrict__ Kb, ushort* __restrict__ Vtb,
    float* __restrict__ outF)
{
  constexpr int BN  = (MODE==0) ? 256 : 128;
  constexpr int NJ  = BN/64;          // n-frags per wave (4 or 2)
  constexpr int NHB = BN/128;         // B half-tiles (2 or 1)

  __shared__ __align__(16) ushort As[2][2][8192];     // [dbuf][half][row*64+col]
  __shared__ __align__(16) ushort Bs[2][NHB][8192];

  const int t = threadIdx.x;
  const int l = t & 63, w = t >> 6;
  const int wr = w >> 2, wc = w & 3;
  const int li = l & 15, c4 = l >> 4;

  // raster: m-supertiles of 4 x all-n, bijective XCD chunking
  int m0, n0;
  if (MODE==0) {
    int swz = (blockIdx.x & 7) * 48 + (blockIdx.x >> 3);   // 384 blocks
    int ms = swz / 48, rem = swz % 48;
    m0 = (ms*4 + (rem & 3)) * 256;  n0 = (rem >> 2) * 256;
  } else {
    int swz = (blockIdx.x & 7) * 32 + (blockIdx.x >> 3);   // 256 blocks
    int ms = swz / 32, rem = swz % 32;
    m0 = (ms*4 + (rem & 3)) * 256;  n0 = (rem >> 2) * 128;
  }

  f32x4 acc[8][NJ];
  #pragma unroll
  for (int i=0;i<8;i++)
    #pragma unroll
    for (int j=0;j<NJ;j++) acc[i][j] = (f32x4)0.0f;

  // STAGE one K-tile (BK=64) into dbuf `buf`: linear LDS dest, source column
  // chunk XOR-permuted within the 128B row.
  auto STAGE = [&](int buf, int kk) {
    #pragma unroll
    for (int p = 0; p < 4; ++p) {           // A: 2 halves x 2 chunks/thread
      int hh = p >> 1, n = (p & 1)*512 + t; // n = chunk idx in half (1024)
      int row = n >> 3, jj = (n & 7) ^ (row & 7);
      gld16(&A[(size_t)(m0 + hh*128 + row)*1024 + kk + jj*8], &As[buf][hh][n*8]);
    }
    #pragma unroll
    for (int p = 0; p < 2*NHB; ++p) {
      int hh = p >> 1, n = (p & 1)*512 + t;
      int row = n >> 3, jj = (n & 7) ^ (row & 7);
      gld16(&Bw[(size_t)(n0 + hh*128 + row)*1024 + kk + jj*8], &Bs[buf][hh][n*8]);
    }
  };

  STAGE(0, 0);
  STAGE(1, 64);
  if constexpr (MODE==0) asm volatile("s_waitcnt vmcnt(8)" ::: "memory");
  else                   asm volatile("s_waitcnt vmcnt(6)" ::: "memory");
  __builtin_amdgcn_s_barrier();
  __builtin_amdgcn_sched_barrier(0);

  #pragma unroll 2
  for (int kt = 0; kt < 16; ++kt) {
    const int cur = kt & 1;
    // ---- 4 quadrant phases: ds_read frags + 16 MFMA each (compiler lgkm) ----
    #pragma unroll
    for (int q = 0; q < 4; ++q) {
      const int qm = q >> 1, qn = q & 1;
      short8 af[4][2], bf[NJ/2][2];
      #pragma unroll
      for (int i=0;i<4;i++) {
        int row = (qm*4 + i)*16 + li;
        #pragma unroll
        for (int ks=0;ks<2;ks++)
          af[i][ks] = *(const short8*)&As[cur][wr][row*64 + (((ks*4+c4) ^ (li&7))*8)];
      }
      #pragma unroll
      for (int jj=0;jj<NJ/2;jj++) {
        int jg = wc*NJ + qn*(NJ/2) + jj;
        int rowB = (jg & 7)*16 + li;
        #pragma unroll
        for (int ks=0;ks<2;ks++)
          bf[jj][ks] = *(const short8*)&Bs[cur][jg>>3][rowB*64 + (((ks*4+c4) ^ (li&7))*8)];
      }
      __builtin_amdgcn_s_setprio(1);
      #pragma unroll
      for (int i=0;i<4;i++)
        #pragma unroll
        for (int jj=0;jj<NJ/2;jj++)
          #pragma unroll
          for (int ks=0;ks<2;ks++)
            acc[qm*4+i][qn*(NJ/2)+jj] =
              __builtin_amdgcn_mfma_f32_16x16x32_bf16(af[i][ks], bf[jj][ks],
                                                      acc[qm*4+i][qn*(NJ/2)+jj], 0,0,0);
      __builtin_amdgcn_s_setprio(0);
    }
    // ---- all waves done reading buf[cur] -> restage it with tile kt+2 ----
    __builtin_amdgcn_s_barrier();
    __builtin_amdgcn_sched_barrier(0);
    STAGE(cur, ((kt + 2) & 15) * 64);      // wraparound dummy on tail, never read
    if constexpr (MODE==0) asm volatile("s_waitcnt vmcnt(8)" ::: "memory");
    else                   asm volatile("s_waitcnt vmcnt(6)" ::: "memory");
    __builtin_amdgcn_s_barrier();          // all waves' tile kt+1 loads landed
    __builtin_amdgcn_sched_barrier(0);
  }

  #pragma unroll
  for (int i=0;i<8;i++) {
    int rbase = m0 + wr*128 + i*16 + c4*4;
    #pragma unroll
    for (int j=0;j<NJ;j++) {
      int col = n0 + wc*(BN/4) + j*16 + li;
      float bv = bias[col];
      if (MODE == 0) {
        int p = col >> 10, h = (col >> 6) & 15, d = col & 63;
        int b = rbase >> 10, s = rbase & 1023;
        if (p == 2) {          // V -> transposed [bh][d][s], 8B packed store
          ushort pk4[4];
          #pragma unroll
          for (int r=0;r<4;r++) pk4[r] = f2b(acc[i][j][r] + bv);
          *(uint2*)&Vtb[((size_t)((b*16+h)*64 + d))*1024 + s] = *(uint2*)pk4;
        } else {
          ushort* dst = (p==0) ? Qb : Kb;
          float sc = (p==0) ? 0.18033688011112042f : 1.0f;   // 0.125*log2(e)
          #pragma unroll
          for (int r=0;r<4;r++)
            dst[(((size_t)(b*16 + h))*1024 + s + r)*64 + d] = f2b((acc[i][j][r] + bv) * sc);
        }
      } else {
        #pragma unroll
        for (int r=0;r<4;r++)
          outF[(size_t)(rbase+r)*1024 + col] = acc[i][j][r] + bv;
      }
    }
  }
}

// ---------------- causal flash attention, wave-independent ----------------
// 1024 blocks x 256 thr; wave w handles q-tile {j,15-j,16+j,31-j}[w] of head bh.
// No __syncthreads. 32x32x16 MFMAs; swapped QK^T (S[kv][q]) and swapped PV
// (O[d][q]) so softmax state is per-lane scalar + one shfl_xor(32).
// Scores in log2 domain (scale folded into Q).
__global__ __launch_bounds__(256, 3) void attn_kern(
    const ushort* __restrict__ Qb, const ushort* __restrict__ Kb,
    const ushort* __restrict__ Vt, ushort* __restrict__ Ob)
{
  __shared__ __align__(16) ushort Pb[4][32*40];   // per-wave P [q][kv], stride 40
  __shared__ __align__(16) ushort OT[4][32*72];   // per-wave epilogue transpose
  const int t = threadIdx.x, l = t & 63, w = t >> 6;
  const int bid = blockIdx.x;
  const int x = bid & 7, i0 = bid >> 3;
  const int bh = x*16 + (i0 >> 3), j = i0 & 7;     // bh clustered per XCD
  int qt;
  if      (w == 0) qt = j;
  else if (w == 1) qt = 15 - j;
  else if (w == 2) qt = 16 + j;
  else             qt = 31 - j;

  const int col = l & 31, hi = l >> 5;
  const ushort* Qp = Qb + (size_t)bh*65536;
  const ushort* Kp = Kb + (size_t)bh*65536;
  const ushort* Vp = Vt + (size_t)bh*65536;

  short8 qf[4];
  #pragma unroll
  for (int m=0;m<4;m++)
    qf[m] = *(const short8*)&Qp[(size_t)(qt*32+col)*64 + m*16 + hi*8];

  f32x16 accO0 = (f32x16)0.0f, accO1 = (f32x16)0.0f;
  float mR = -1e30f, lS = 0.0f;

  ushort* Pw = &Pb[w][0];
  const int nt = qt + 1;
  for (int kt = 0; kt < nt; ++kt) {
    short8 kf[4], vf0[2], vf1[2];
    #pragma unroll
    for (int m=0;m<4;m++)
      kf[m] = *(const short8*)&Kp[(size_t)(kt*32+col)*64 + m*16 + hi*8];
    #pragma unroll
    for (int m=0;m<2;m++) {
      vf0[m] = *(const short8*)&Vp[(size_t)col*1024      + kt*32 + m*16 + hi*8];
      vf1[m] = *(const short8*)&Vp[(size_t)(32+col)*1024 + kt*32 + m*16 + hi*8];
    }

    f32x16 s = (f32x16)0.0f;
    #pragma unroll
    for (int m=0;m<4;m++)
      s = __builtin_amdgcn_mfma_f32_32x32x16_bf16(kf[m], qf[m], s, 0, 0, 0);

    if (kt == qt) {                       // diagonal tile: causal mask
      #pragma unroll
      for (int r=0;r<16;r++) {
        int kvl = (r&3) + ((r>>2)<<3) + 4*hi;
        s[r] = (kvl > col) ? -1e9f : s[r];
      }
    }

    float mx = s[0];
    #pragma unroll
    for (int r=1;r<16;r++) mx = fmaxf(mx, s[r]);
    mx = fmaxf(mx, __shfl_xor(mx, 32));   // combine kv-halves (lane i <-> i+32)

    if (__any(mx - mR > 8.0f)) {          // T13 defer-max (log2 units)
      float mN = fmaxf(mR, mx);
      float corr = __builtin_amdgcn_exp2f(mR - mN);
      mR = mN; lS *= corr;
      #pragma unroll
      for (int r=0;r<16;r++) { accO0[r] *= corr; accO1[r] *= corr; }
    }

    float p[16], rs = 0.0f;
    #pragma unroll
    for (int r=0;r<16;r++) { p[r] = __builtin_amdgcn_exp2f(s[r] - mR); rs += p[r]; }
    rs += __shfl_xor(rs, 32);
    lS += rs;

    // P -> per-wave LDS [q][kv] (packed pair writes), then B-fragment reads
    #pragma unroll
    for (int r2=0;r2<8;r2++) {
      int r = 2*r2;
      int kv = (r&3) + ((r>>2)<<3) + 4*hi;          // even; pair (kv, kv+1)
      *(unsigned*)&Pw[col*40 + kv] = pk2(p[r], p[r+1]);
    }
    short8 pb0 = *(const short8*)&Pw[col*40 + hi*8];        // kv 0..15 slice
    short8 pb1 = *(const short8*)&Pw[col*40 + 16 + hi*8];   // kv 16..31 slice

    accO0 = __builtin_amdgcn_mfma_f32_32x32x16_bf16(vf0[0], pb0, accO0, 0,0,0);
    accO0 = __builtin_amdgcn_mfma_f32_32x32x16_bf16(vf0[1], pb1, accO0, 0,0,0);
    accO1 = __builtin_amdgcn_mfma_f32_32x32x16_bf16(vf1[0], pb0, accO1, 0,0,0);
    accO1 = __builtin_amdgcn_mfma_f32_32x32x16_bf16(vf1[1], pb1, accO1, 0,0,0);
  }

  // epilogue: O[dv][q] regs -> LDS transpose -> coalesced global store
  float inv = 1.0f / lS;
  ushort* o = &OT[w][0];
  #pragma unroll
  for (int r2=0;r2<8;r2++) {
    int r = 2*r2;
    int dv = (r&3) + ((r>>2)<<3) + 4*hi;
    *(unsigned*)&o[col*72 + dv]      = pk2(accO0[r]*inv, accO0[r+1]*inv);
    *(unsigned*)&o[col*72 + 32 + dv] = pk2(accO1[r]*inv, accO1[r+1]*inv);
  }
  const int b = bh >> 4, h = bh & 15;
  #pragma unroll
  for (int it=0; it<4; ++it) {
    int q = it*8 + (l>>3), c8 = (l&7)*8;
    uint4 v = *(const uint4*)&o[q*72 + c8];
    int qg = qt*32 + q;
    *(uint4*)&Ob[(size_t)(b*1024+qg)*1024 + h*64 + c8] = v;
  }
}

extern "C" void kernel_launch(void* const* d_in, const int* in_sizes, int n_in,
                              void* d_out, int out_size, void* d_ws, size_t ws_size,
                              hipStream_t stream) {
  const float* query = (const float*)d_in[0];
  const float* Wq = (const float*)d_in[4];
  const float* bq = (const float*)d_in[5];
  const float* Wk = (const float*)d_in[6];
  const float* bk = (const float*)d_in[7];
  const float* Wv = (const float*)d_in[8];
  const float* bv = (const float*)d_in[9];
  const float* Wo = (const float*)d_in[10];
  const float* bo = (const float*)d_in[11];

  char* wsb = (char*)d_ws;
  ushort* Xb   = (ushort*)(wsb);                  // 16 MB
  ushort* Wqkv = (ushort*)(wsb + 16777216);       // 6 MB
  float*  Bqkv = (float*) (wsb + 23068672);       // 12 KB
  ushort* Wob  = (ushort*)(wsb + 23080960);       // 2 MB
  ushort* Qb   = (ushort*)(wsb + 25178112);       // 16 MB
  ushort* Kb   = (ushort*)(wsb + 41955328);       // 16 MB
  ushort* Vtb  = (ushort*)(wsb + 58732544);       // 16 MB  [bh][d][s]
  ushort* Ob   = (ushort*)(wsb + 75509760);       // 16 MB

  hipLaunchKernelGGL(pack_x_kern, dim3(4096), dim3(256), 0, stream, query, Xb);
  hipLaunchKernelGGL(pack_w_kern, dim3(1024), dim3(256), 0, stream,
                     Wq, Wk, Wv, bq, bk, bv, Wo, Wqkv, Bqkv, Wob);
  hipLaunchKernelGGL(gemm8p_kern<0>, dim3(384), dim3(512), 0, stream,
                     Xb, Wqkv, Bqkv, Qb, Kb, Vtb, (float*)nullptr);
  hipLaunchKernelGGL(attn_kern, dim3(1024), dim3(256), 0, stream, Qb, Kb, Vtb, Ob);
  hipLaunchKernelGGL(gemm8p_kern<1>, dim3(256), dim3(512), 0, stream,
                     Ob, Wob, bo, (ushort*)nullptr, (ushort*)nullptr, (ushort*)nullptr,
                     (float*)d_out);
}